// Round 9
// baseline (299.787 us; speedup 1.0000x reference)
//
#include <hip/hip_runtime.h>

typedef unsigned short ushort;

typedef __bf16 bf16x8 __attribute__((ext_vector_type(8)));
typedef float  f32x4  __attribute__((ext_vector_type(4)));
typedef float  f32x2  __attribute__((ext_vector_type(2)));
typedef unsigned short u16x8 __attribute__((ext_vector_type(8)));
typedef unsigned short u16x4 __attribute__((ext_vector_type(4)));
typedef unsigned int   u32x2 __attribute__((ext_vector_type(2)));

static constexpr int BB   = 32;
static constexpr int NN   = 577;   // N = NP+1
static constexpr int LL   = 576;   // NP
static constexpr int DIMC = 512;
static constexpr int BN   = BB * NN;  // 18464

// ---------------- workspace arena (bytes), total 98,828,288 (~94.3 MB) -----
// EMA chunk-states (16.8 MB) live in the AO region (dead until k_fattn).
static constexpr size_t SZ_WQKVT = 1536ull * 512 * 2;
static constexpr size_t SZ_WOUTT = 512ull * 512 * 2;
static constexpr size_t SZ_QK    = (size_t)BN * 1024 * 2;    // 37,814,272
static constexpr size_t SZ_V     = (size_t)BN * 512 * 2;     // 18,907,136
static constexpr size_t SZ_VT    = 256ull * 64 * 640 * 2;    // 20,971,520
static constexpr size_t OFF_WQKVT = 0;
static constexpr size_t OFF_WOUTT = OFF_WQKVT + SZ_WQKVT;
static constexpr size_t OFF_QTAB  = OFF_WOUTT + SZ_WOUTT;
static constexpr size_t OFF_CTAB  = OFF_QTAB + 65536;
static constexpr size_t OFF_QK    = OFF_CTAB + 65536;
static constexpr size_t OFF_V     = OFF_QK + SZ_QK;
static constexpr size_t OFF_REGION= OFF_V + SZ_V;
static constexpr size_t OFF_XM    = OFF_REGION;              // xm dead after k_qkv
static constexpr size_t OFF_VT    = OFF_REGION;              // vt overlays xm
static constexpr size_t OFF_AO    = OFF_REGION + SZ_VT;
static constexpr size_t OFF_ST    = OFF_AO;                  // EMA states overlay ao
static constexpr size_t WS_NEEDED = OFF_AO + SZ_V;           // 98,828,288

// ---------------- helpers ----------------
__device__ __forceinline__ ushort bf16bits(float f) {
  unsigned int u = __builtin_bit_cast(unsigned int, f);
  u = (u + 0x7fffu + ((u >> 16) & 1u)) >> 16;
  return (ushort)u;
}
// RNE bf16 pair-pack: same bits as (bf16bits(lo) | bf16bits(hi)<<16).
__device__ __forceinline__ unsigned int bf16pk(float lo, float hi) {
  unsigned int u0 = __builtin_bit_cast(unsigned int, lo);
  unsigned int u1 = __builtin_bit_cast(unsigned int, hi);
  unsigned int a0 = u0 + 0x7fffu + ((u0 >> 16) & 1u);
  unsigned int a1 = u1 + 0x7fffu + ((u1 >> 16) & 1u);
  return __builtin_amdgcn_perm(a1, a0, 0x07060302);   // {a1.hi16, a0.hi16}
}
__device__ __forceinline__ float sigmoidf_(float z) { return 1.f / (1.f + __expf(-z)); }
__device__ __forceinline__ float siluf(float z)     { return z / (1.f + __expf(-z)); }
// async global->LDS, 16B per lane; linear LDS dest (base+lane*16), per-lane
// global src (pre-swizzled).
__device__ __forceinline__ void gload16(const ushort* g, ushort* l) {
  __builtin_amdgcn_global_load_lds(
      (const __attribute__((address_space(1))) unsigned int*)g,
      (__attribute__((address_space(3))) unsigned int*)l, 16, 0, 0);
}

// ---------------- prep: EMA tables + bf16 transposed weights ----------------
__global__ __launch_bounds__(256) void k_prep(
    const float* __restrict__ delta, const float* __restrict__ alpha,
    const float* __restrict__ beta,  const float* __restrict__ gamma,
    const float* __restrict__ Wqk,   const float* __restrict__ Wv,
    const float* __restrict__ Wout,
    float* __restrict__ qtab, float* __restrict__ ctab,
    ushort* __restrict__ Wqkvt, ushort* __restrict__ Woutt)
{
  int idx = blockIdx.x * 256 + threadIdx.x;
  if (idx < 16384) {
    float p = sigmoidf_(delta[idx]);
    float q = 1.f - p * sigmoidf_(alpha[idx]);
    qtab[idx] = q;
    ctab[idx] = p * beta[idx] * gamma[idx] * 0.25f;   // scale = sqrt(1/16)
  }
  int i2 = idx - 16384;                                // Wqkv_t: [1536][512]
  if (i2 >= 0 && i2 < 1536 * 512) {
    int n = i2 >> 9, k = i2 & 511;
    float w = (n < 1024) ? Wqk[k * 1024 + n] : Wv[k * 512 + (n - 1024)];
    Wqkvt[i2] = bf16bits(w);
  }
  int i3 = i2 - 1536 * 512;                            // Wout_t: [512][512]
  if (i3 >= 0 && i3 < 512 * 512) {
    int n = i3 >> 9, k = i3 & 511;
    Woutt[i3] = bf16bits(Wout[k * 512 + n]);
  }
}

// ======== chunked EMA scan (linear recurrence, q in (0,1)) =================
// f32x2[8] + elementwise_fma so LLVM can select dual-issue v_pk_fma_f32.
// st: [(dir*32+b)*8+chunk][n16][d512] f32.

// ---- pass 1: chunk-local final states, chunks 0..6 each direction --------
__global__ __launch_bounds__(64) void k_ema_p1(
    const float* __restrict__ x, const float* __restrict__ qtab,
    float* __restrict__ st)
{
  const int gx = blockIdx.x, cy = blockIdx.y, b = blockIdx.z;
  if (gx < 8) {
    const int d = gx * 64 + threadIdx.x;
    f32x2 q[8], h[8];
    #pragma unroll
    for (int n = 0; n < 8; ++n) {
      q[n] = *(const f32x2*)(qtab + d * 16 + 2 * n);
      h[n] = (f32x2){0.f, 0.f};
    }
    const float* xp = x + ((size_t)b * NN + 1) * DIMC + d;
    const int blo = cy * 9;
    float xn[8];
    #pragma unroll
    for (int u = 0; u < 8; ++u) xn[u] = xp[(blo * 8 + u) * DIMC];
    for (int blk = blo; blk < blo + 9; ++blk) {
      float xv[8];
      #pragma unroll
      for (int u = 0; u < 8; ++u) xv[u] = xn[u];
      if (blk < blo + 8) {
        #pragma unroll
        for (int u = 0; u < 8; ++u) xn[u] = xp[((blk + 1) * 8 + u) * DIMC];
      }
      #pragma unroll
      for (int u = 0; u < 8; ++u) {
        f32x2 x2 = {xv[u], xv[u]};
        #pragma unroll
        for (int n = 0; n < 8; ++n) h[n] = __builtin_elementwise_fma(q[n], h[n], x2);
      }
    }
    float* sp = st + (((size_t)b * 8 + cy) * 16) * 512 + d;
    #pragma unroll
    for (int n = 0; n < 8; ++n) { sp[(2*n) * 512] = h[n][0]; sp[(2*n+1) * 512] = h[n][1]; }
  } else {
    const int d = (gx - 8) * 64 + threadIdx.x;
    f32x2 q[8], g[8];
    #pragma unroll
    for (int n = 0; n < 8; ++n) {
      q[n] = *(const f32x2*)(qtab + (d + 512) * 16 + 2 * n);
      g[n] = (f32x2){0.f, 0.f};
    }
    const float* xp = x + ((size_t)b * NN + 1) * DIMC + d;
    const int blo = (7 - cy) * 9;
    float xn[8];
    #pragma unroll
    for (int u = 0; u < 8; ++u) xn[u] = xp[((blo + 8) * 8 + u) * DIMC];
    for (int blk = blo + 8; blk >= blo; --blk) {
      float xv[8];
      #pragma unroll
      for (int u = 0; u < 8; ++u) xv[u] = xn[u];
      if (blk > blo) {
        #pragma unroll
        for (int u = 0; u < 8; ++u) xn[u] = xp[((blk - 1) * 8 + u) * DIMC];
      }
      #pragma unroll
      for (int u = 7; u >= 0; --u) {
        f32x2 x2 = {xv[u], xv[u]};
        #pragma unroll
        for (int n = 0; n < 8; ++n) g[n] = __builtin_elementwise_fma(q[n], g[n], x2);
      }
    }
    float* sp = st + (((size_t)(32 + b) * 8 + cy) * 16) * 512 + d;
    #pragma unroll
    for (int n = 0; n < 8; ++n) { sp[(2*n) * 512] = g[n][0]; sp[(2*n+1) * 512] = g[n][1]; }
  }
}

// ---- mid: exclusive scan over chunk states with q^72 ----------------------
__global__ __launch_bounds__(256) void k_ema_mid(
    const float* __restrict__ qtab, float* __restrict__ st)
{
  int idx = blockIdx.x * 256 + threadIdx.x;   // 524,288 = 64*16*512
  int d = idx & 511;
  int rest = idx >> 9;          // db*16 + n
  int n = rest & 15;
  int db = rest >> 4;           // dir*32 + b
  int dir = db >> 5;
  float q = qtab[(((size_t)dir << 9) + d) * 16 + n];
  float q2 = q * q, q4 = q2 * q2, q8 = q4 * q4;
  float q16 = q8 * q8, q32 = q16 * q16, q64 = q32 * q32;
  float qL = q64 * q8;          // q^72
  float h = 0.f;
  float* sp = st + ((size_t)db * 128 + n) * 512 + d;
  #pragma unroll
  for (int c = 0; c < 8; ++c) {
    float tmp = (c < 7) ? sp[c * 8192] : 0.f;   // chunk stride 16*512
    sp[c * 8192] = h;
    h = fmaf(qL, h, tmp);
  }
}

// ---- fused pass 3: bwd (y2->LDS fp16) then fwd + combine + silu -> xm -----
__global__ __launch_bounds__(64) void k_ema_fuse(
    const float* __restrict__ x, const float* __restrict__ qtab,
    const float* __restrict__ ctab, const float* __restrict__ st,
    const float* __restrict__ omega, ushort* __restrict__ xm)
{
  __shared__ _Float16 yb[72 * 64];   // 9,216 B
  const int lane = threadIdx.x;
  const int gx = blockIdx.x, cy = blockIdx.y, b = blockIdx.z;
  const int d = gx * 64 + lane;
  const float* xp = x + ((size_t)b * NN + 1 + cy * 72) * DIMC + d;
  { // backward pass over this chunk's 72 rows
    f32x2 q[8], c[8], g[8];
    const float* sp = st + (((size_t)(32 + b) * 8 + (7 - cy)) * 16) * 512 + d;
    #pragma unroll
    for (int n = 0; n < 8; ++n) {
      q[n] = *(const f32x2*)(qtab + (d + 512) * 16 + 2 * n);
      c[n] = *(const f32x2*)(ctab + (d + 512) * 16 + 2 * n);
      g[n] = (f32x2){sp[(2*n) * 512], sp[(2*n+1) * 512]};
    }
    float xn[8];
    #pragma unroll
    for (int u = 0; u < 8; ++u) xn[u] = xp[(64 + u) * DIMC];
    for (int blk = 8; blk >= 0; --blk) {
      float xv[8];
      #pragma unroll
      for (int u = 0; u < 8; ++u) xv[u] = xn[u];
      if (blk > 0) {
        #pragma unroll
        for (int u = 0; u < 8; ++u) xn[u] = xp[((blk - 1) * 8 + u) * DIMC];
      }
      #pragma unroll
      for (int u = 7; u >= 0; --u) {
        f32x2 x2 = {xv[u], xv[u]};
        f32x2 yv = {0.f, 0.f};
        #pragma unroll
        for (int n = 0; n < 8; ++n) {
          g[n] = __builtin_elementwise_fma(q[n], g[n], x2);
          yv   = __builtin_elementwise_fma(c[n], g[n], yv);
        }
        yb[(blk * 8 + u) * 64 + lane] = (_Float16)(yv[0] + yv[1]);
      }
    }
  }
  __syncthreads();
  { // forward pass + combine
    f32x2 q[8], c[8], h[8];
    const float* sp = st + (((size_t)b * 8 + cy) * 16) * 512 + d;
    #pragma unroll
    for (int n = 0; n < 8; ++n) {
      q[n] = *(const f32x2*)(qtab + d * 16 + 2 * n);
      c[n] = *(const f32x2*)(ctab + d * 16 + 2 * n);
      h[n] = (f32x2){sp[(2*n) * 512], sp[(2*n+1) * 512]};
    }
    const float om = omega[d];
    ushort* op = xm + ((size_t)b * NN + 1 + cy * 72) * DIMC + d;
    float xn[8];
    #pragma unroll
    for (int u = 0; u < 8; ++u) xn[u] = xp[u * DIMC];
    for (int blk = 0; blk < 9; ++blk) {
      float xv[8];
      #pragma unroll
      for (int u = 0; u < 8; ++u) xv[u] = xn[u];
      if (blk < 8) {
        #pragma unroll
        for (int u = 0; u < 8; ++u) xn[u] = xp[((blk + 1) * 8 + u) * DIMC];
      }
      #pragma unroll
      for (int u = 0; u < 8; ++u) {
        f32x2 x2 = {xv[u], xv[u]};
        f32x2 yv = {0.f, 0.f};
        #pragma unroll
        for (int n = 0; n < 8; ++n) {
          h[n] = __builtin_elementwise_fma(q[n], h[n], x2);
          yv   = __builtin_elementwise_fma(c[n], h[n], yv);
        }
        float s = (yv[0] + yv[1]) + (float)yb[(blk * 8 + u) * 64 + lane] + xv[u] * om;
        op[(blk * 8 + u) * DIMC] = bf16bits(siluf(s));
      }
    }
  }
  if (cy == 0) {   // cls row passthrough
    size_t e0 = ((size_t)b * NN) * DIMC + d;
    xm[e0] = bf16bits(x[e0]);
  }
}

// ---------------- QKV GEMM: xm[18464,512] @ Wqkv_t[1536,512]^T -------------
// global_load_lds staging; LINEAR LDS [128][32]; source col pre-swizzled by
// (row&3), same XOR on MFMA read. q cols pre-scaled by 0.125*log2(e).
// XCD-chunked block remap (bijective, nwg=1740).
// EPILOGUE: LDS-staged coalesced stores (u16x8/lane) -- replaces 64 scalar
// 2-byte global stores per thread (4x32B fragments per wave instr).
__global__ __launch_bounds__(256) void k_qkv(
    const ushort* __restrict__ A, const ushort* __restrict__ Bt,
    ushort* __restrict__ qk, ushort* __restrict__ v)
{
  __shared__ alignas(16) ushort lsh[8192];     // 16 KB: lA | lB, reused by epilogue
  ushort* lA = lsh;
  ushort* lB = lsh + 4096;
  const int tid = threadIdx.x, wv = tid >> 6, lane = tid & 63;
  const int quad = lane >> 4, c16 = lane & 15;
  const int fid = blockIdx.y * 12 + blockIdx.x;        // dispatch-order id
  const int xcd = fid & 7, ord = fid >> 3;             // nwg=1740: q=217,r=4
  const int wg  = (xcd < 4 ? xcd * 218 : 872 + (xcd - 4) * 217) + ord;
  const int row0 = (wg / 12) * 128, n0 = (wg % 12) * 128;
  const int wm = (wv >> 1) * 64, wn = (wv & 1) * 64;
  const int sr  = wv * 32 + (lane >> 2);
  const int scs = ((lane & 3) ^ (sr & 3)) * 8;         // source col swizzle
  int ga[2], gb[2];
  #pragma unroll
  for (int s = 0; s < 2; ++s) {
    int r = row0 + sr + s * 16; if (r > BN - 1) r = BN - 1;
    ga[s] = r;
    gb[s] = n0 + sr + s * 16;
  }
  const int xread = (quad ^ (c16 & 3)) * 8;            // MFMA read swizzle
  f32x4 z4 = {0.f, 0.f, 0.f, 0.f};
  f32x4 acc[4][4];
  #pragma unroll
  for (int mi = 0; mi < 4; ++mi)
    #pragma unroll
    for (int ni = 0; ni < 4; ++ni) acc[mi][ni] = z4;

  for (int kt = 0; kt < 16; ++kt) {
    const int k0 = kt * 32;
    __syncthreads();                 // prior MFMA reads done
    #pragma unroll
    for (int s = 0; s < 2; ++s) {
      gload16(A  + (size_t)ga[s] * 512 + k0 + scs, lA + (wv * 32 + s * 16) * 32);
      gload16(Bt + (size_t)gb[s] * 512 + k0 + scs, lB + (wv * 32 + s * 16) * 32);
    }
    __syncthreads();                 // vmcnt drained -> tile visible
    bf16x8 af[4], bfv[4];
    #pragma unroll
    for (int mi = 0; mi < 4; ++mi)
      af[mi] = *(const bf16x8*)(lA + (wm + mi * 16 + c16) * 32 + xread);
    #pragma unroll
    for (int ni = 0; ni < 4; ++ni)
      bfv[ni] = *(const bf16x8*)(lB + (wn + ni * 16 + c16) * 32 + xread);
    #pragma unroll
    for (int mi = 0; mi < 4; ++mi)
      #pragma unroll
      for (int ni = 0; ni < 4; ++ni)
        acc[mi][ni] = __builtin_amdgcn_mfma_f32_16x16x32_bf16(af[mi], bfv[ni], acc[mi][ni], 0, 0, 0);
  }
  const bool isv = (n0 >= 1024);
  const float osc = (n0 < 512) ? 0.1803368801111f : 1.0f;  // 0.125*log2(e)
  // ---- epilogue: stage half-tile [64][128] bf16 in lsh, store coalesced
  #pragma unroll
  for (int hh = 0; hh < 2; ++hh) {
    __syncthreads();                 // prior half's readers / MFMA reads done
    if ((wv >> 1) == hh) {
      #pragma unroll
      for (int mi = 0; mi < 4; ++mi)
        #pragma unroll
        for (int r = 0; r < 4; ++r) {
          int lrow = mi * 16 + quad * 4 + r;           // 0..63 within half
          #pragma unroll
          for (int ni = 0; ni < 4; ++ni)
            lsh[lrow * 128 + wn + ni * 16 + c16] = bf16bits(acc[mi][ni][r] * osc);
        }
    }
    __syncthreads();                 // half-tile visible
    #pragma unroll
    for (int pass = 0; pass < 4; ++pass) {
      int lrow = pass * 16 + (tid >> 4);
      int cc = (tid & 15) * 8;
      int grow = row0 + hh * 64 + lrow;
      if (grow < BN) {
        u16x8 val = *(const u16x8*)(lsh + lrow * 128 + cc);
        if (!isv) *(u16x8*)(qk + (size_t)grow * 1024 + n0 + cc) = val;
        else      *(u16x8*)(v  + (size_t)grow * 512 + (n0 - 1024) + cc) = val;
      }
    }
  }
}

// ---------------- transpose v -> vt[bh*64+dh][640] (zero-padded j>=577) ----
__global__ __launch_bounds__(256) void k_vtrans(
    const ushort* __restrict__ v, ushort* __restrict__ vt)
{
  __shared__ alignas(16) ushort lt[64 * 72];
  const int tid = threadIdx.x;
  const int bh = blockIdx.y, b = bh >> 3, h = bh & 7;
  const int j0 = blockIdx.x * 64;
  #pragma unroll
  for (int pass = 0; pass < 2; ++pass) {
    int cch = pass * 256 + tid;
    int jl = cch >> 3, cc = cch & 7;
    int gj = j0 + jl;
    u16x8 val = {0, 0, 0, 0, 0, 0, 0, 0};
    if (gj < 577) val = *(const u16x8*)(v + ((size_t)(b * NN + gj)) * 512 + h * 64 + cc * 8);
    *(u16x8*)(lt + jl * 72 + cc * 8) = val;
  }
  __syncthreads();
  #pragma unroll
  for (int pass = 0; pass < 2; ++pass) {
    int cch = pass * 256 + tid;
    int dh = cch >> 3, jc = cch & 7;
    u16x8 o;
    #pragma unroll
    for (int e = 0; e < 8; ++e) o[e] = lt[(jc * 8 + e) * 72 + dh];
    *(u16x8*)(vt + ((size_t)(bh * 64 + dh)) * 640 + j0 + jc * 8) = o;
  }
}

// -------- fused flash attention: O = softmax(QK^T) V + Bias V --------------
// r6 version VERBATIM (measured 79.2 us; r8's gload_lds-dbuf regressed to
// 84.9 -- the reg-prefetch + short ds_write burst keeps loads in flight
// across the barrier without queue-drain serialization).
// Static softmax; Q pre-scaled by 0.125*log2(e) -> raw exp2. Swapped QK^T
// (mfma(K,Q) -> S^T) + RNE pair-pack via v_perm + 8-byte lp writes.
// 2 barriers/tile (lp wave-private). K/V prefetch issued right after
// staging barrier. Grid (bh, itile): all 5 i-tiles of a bh on one XCD.
__global__ __launch_bounds__(256) void k_fattn(
    const ushort* __restrict__ qk, const ushort* __restrict__ vt,
    const float* __restrict__ relb, ushort* __restrict__ ao)
{
  __shared__ alignas(16) ushort lk[64 * 64];
  __shared__ alignas(16) ushort lv[64 * 64];
  __shared__ alignas(16) ushort lp[128 * 64];
  __shared__ ushort lbias16[1280];     // bf16 bias at +64 offset, pad-safe
  const int tid = threadIdx.x, wv = tid >> 6, lane = tid & 63;
  const int quad = lane >> 4, c16 = lane & 15;
  const int bh = blockIdx.x, b = bh >> 3, h = bh & 7;
  const int i0 = blockIdx.y * 128, wm = wv * 32;
  for (int t = tid; t < 1280; t += 256) {
    int idx = t - 64;
    lbias16[t] = (idx >= 0 && idx < 1153) ? bf16bits(relb[idx]) : (ushort)0;
  }
  // Q fragments in registers for the whole block (rows wm+ms*16+c16)
  bf16x8 aq[2][2];
  #pragma unroll
  for (int ms = 0; ms < 2; ++ms) {
    int gi = i0 + wm + ms * 16 + c16; if (gi > 576) gi = 576;
    const ushort* qp = qk + ((size_t)(b * NN + gi)) * 1024 + h * 64;
    #pragma unroll
    for (int kk = 0; kk < 2; ++kk)
      aq[ms][kk] = *(const bf16x8*)(qp + (kk * 4 + quad) * 8);
  }
  const int s_r = tid >> 3, s_c = tid & 7;
  const ushort* kbase = qk + ((size_t)b * NN) * 1024 + 512 + h * 64 + s_c * 8;
  const ushort* vbase = vt + ((size_t)bh * 64) * 640 + s_c * 8;

  float lsum[2] = {0.f, 0.f};
  f32x4 z4 = {0.f, 0.f, 0.f, 0.f};
  f32x4 accp[2][4], accb[2][4];
  #pragma unroll
  for (int ms = 0; ms < 2; ++ms)
    #pragma unroll
    for (int ns = 0; ns < 4; ++ns) { accp[ms][ns] = z4; accb[ms][ns] = z4; }

  // preload tile jt=0 (j = 0..63, no clamp needed)
  u16x8 sk[2], sv[2];
  #pragma unroll
  for (int it = 0; it < 2; ++it) {
    int r = it * 32 + s_r;
    sk[it] = *(const u16x8*)(kbase + (size_t)r * 1024);
    sv[it] = *(const u16x8*)(vbase + (size_t)r * 640);
  }

  for (int jt = 0; jt < 10; ++jt) {
    __syncthreads();                       // prior lk/lv readers done
    #pragma unroll
    for (int it = 0; it < 2; ++it) {
      int r = it * 32 + s_r;
      int pc = (s_c ^ (r & 7)) * 8;
      *(u16x8*)(lk + r * 64 + pc) = sk[it];
      *(u16x8*)(lv + r * 64 + pc) = sv[it];
    }
    __syncthreads();                       // staging visible
    // issue next K/V tile loads NOW: latency hides under QK^T+softmax+PV
    if (jt < 9) {
      const int j0n = (jt + 1) * 64;
      #pragma unroll
      for (int it = 0; it < 2; ++it) {
        int r = it * 32 + s_r;
        int gj = j0n + r; if (gj > 576) gj = 576;
        sk[it] = *(const u16x8*)(kbase + (size_t)gj * 1024);
        sv[it] = *(const u16x8*)(vbase + (size_t)r * 640 + j0n);
      }
    }
    // ---- S^T = K Q^T, one ms (16 q-rows) at a time; softmax fused per ms
    #pragma unroll
    for (int ms = 0; ms < 2; ++ms) {
      f32x4 dacc[4] = {z4, z4, z4, z4};
      #pragma unroll
      for (int kk = 0; kk < 2; ++kk) {
        const int ck = kk * 4 + quad;
        #pragma unroll
        for (int ns = 0; ns < 4; ++ns) {
          const int row = ns * 16 + c16;
          bf16x8 bk = *(const bf16x8*)(lk + row * 64 + ((ck ^ (row & 7)) * 8));
          dacc[ns] = __builtin_amdgcn_mfma_f32_16x16x32_bf16(bk, aq[ms][kk], dacc[ns], 0, 0, 0);
        }
      }
      // lane holds S[i = wm+ms*16+c16][j = j0 + ns*16 + quad*4 + r]
      const int irow = wm + ms * 16 + c16;
      const int xr = irow & 7;
      #pragma unroll
      for (int ns = 0; ns < 4; ++ns) {
        float ex[4];
        #pragma unroll
        for (int r = 0; r < 4; ++r) {
          float e = __builtin_amdgcn_exp2f(dacc[ns][r]);
          if (jt == 9 && (ns * 16 + quad * 4 + r) >= 1) e = 0.f;   // j >= 577
          ex[r] = e;
        }
        lsum[ms] += (ex[0] + ex[1]) + (ex[2] + ex[3]);
        u32x2 pw = { bf16pk(ex[0], ex[1]), bf16pk(ex[2], ex[3]) };
        const int lc = ns * 2 + (quad >> 1);         // logical 8-col chunk
        *(u32x2*)(lp + irow * 64 + ((lc ^ xr) * 8) + (quad & 1) * 4) = pw;
      }
    }
    // (no barrier: each wave reads only its own lp rows; lgkmcnt orders)
    // ---- O += P~ V  and  O_b += Bias V
    const int j0 = jt * 64;
    #pragma unroll
    for (int kk = 0; kk < 2; ++kk) {
      const int ck = kk * 4 + quad;
      bf16x8 ap[2], ab[2];
      #pragma unroll
      for (int ms = 0; ms < 2; ++ms) {
        const int row = wm + ms * 16 + c16;
        ap[ms] = *(const bf16x8*)(lp + row * 64 + ((ck ^ (row & 7)) * 8));
        u16x8 abu;
        const int base = 64 + 576 + j0 + kk * 32 + quad * 8 - (i0 + row);
        #pragma unroll
        for (int e = 0; e < 8; ++e) abu[e] = lbias16[base + e];
        ab[ms] = __builtin_bit_cast(bf16x8, abu);
      }
      #pragma unroll
      for (int ns = 0; ns < 4; ++ns) {
        const int row = ns * 16 + c16;
        bf16x8 bV = *(const bf16x8*)(lv + row * 64 + ((ck ^ (row & 7)) * 8));
        #pragma unroll
        for (int ms = 0; ms < 2; ++ms) {
          accp[ms][ns] = __builtin_amdgcn_mfma_f32_16x16x32_bf16(ap[ms], bV, accp[ms][ns], 0, 0, 0);
          accb[ms][ns] = __builtin_amdgcn_mfma_f32_16x16x32_bf16(ab[ms], bV, accb[ms][ns], 0, 0, 0);
        }
      }
    }
  }
  // ---- epilogue: row sums live per-lane for row c16; reduce across quads,
  // then shfl the needed row's total (rows quad*4+r of the output C-layout).
  float tot[2];
  #pragma unroll
  for (int ms = 0; ms < 2; ++ms) {
    float t = lsum[ms];
    t += __shfl_xor(t, 16);
    t += __shfl_xor(t, 32);
    tot[ms] = t;
  }
  #pragma unroll
  for (int ms = 0; ms < 2; ++ms) {
    #pragma unroll
    for (int r = 0; r < 4; ++r) {
      float li = 1.f / __shfl(tot[ms], quad * 4 + r);
      int ii = i0 + wm + ms * 16 + quad * 4 + r;
      if (ii < 577) {
        #pragma unroll
        for (int ns = 0; ns < 4; ++ns)
          ao[((size_t)(b * NN + ii)) * 512 + h * 64 + ns * 16 + c16] =
              bf16bits(accp[ms][ns][r] * li + accb[ms][ns][r]);
      }
    }
  }
}

// ---------------- out GEMM: ao[18464,512] @ Wout_t[512,512]^T + b_out -----
__global__ __launch_bounds__(256) void k_out(
    const ushort* __restrict__ A, const ushort* __restrict__ Bt,
    const float* __restrict__ bout, float* __restrict__ out)
{
  __shared__ alignas(16) ushort lA[128 * 32];
  __shared__ alignas(16) ushort lB[128 * 32];
  const int tid = threadIdx.x, wv = tid >> 6, lane = tid & 63;
  const int quad = lane >> 4, c16 = lane & 15;
  const int row0 = blockIdx.y * 128, n0 = blockIdx.x * 128;
  const int wm = (wv >> 1) * 64, wn = (wv & 1) * 64;
  const int sr  = wv * 32 + (lane >> 2);
  const int scs = ((lane & 3) ^ (sr & 3)) * 8;
  int ga[2], gb[2];
  #pragma unroll
  for (int s = 0; s < 2; ++s) {
    int r = row0 + sr + s * 16; if (r > BN - 1) r = BN - 1;
    ga[s] = r;
    gb[s] = n0 + sr + s * 16;
  }
  const int xread = (quad ^ (c16 & 3)) * 8;
  f32x4 z4 = {0.f, 0.f, 0.f, 0.f};
  f32x4 acc[4][4];
  #pragma unroll
  for (int mi = 0; mi < 4; ++mi)
    #pragma unroll
    for (int ni = 0; ni < 4; ++ni) acc[mi][ni] = z4;

  for (int kt = 0; kt < 16; ++kt) {
    const int k0 = kt * 32;
    __syncthreads();
    #pragma unroll
    for (int s = 0; s < 2; ++s) {
      gload16(A  + (size_t)ga[s] * 512 + k0 + scs, lA + (wv * 32 + s * 16) * 32);
      gload16(Bt + (size_t)gb[s] * 512 + k0 + scs, lB + (wv * 32 + s * 16) * 32);
    }
    __syncthreads();
    bf16x8 af[4], bfv[4];
    #pragma unroll
    for (int mi = 0; mi < 4; ++mi)
      af[mi] = *(const bf16x8*)(lA + (wm + mi * 16 + c16) * 32 + xread);
    #pragma unroll
    for (int ni = 0; ni < 4; ++ni)
      bfv[ni] = *(const bf16x8*)(lB + (wn + ni * 16 + c16) * 32 + xread);
    #pragma unroll
    for (int mi = 0; mi < 4; ++mi)
      #pragma unroll
      for (int ni = 0; ni < 4; ++ni)
        acc[mi][ni] = __builtin_amdgcn_mfma_f32_16x16x32_bf16(af[mi], bfv[ni], acc[mi][ni], 0, 0, 0);
  }
  #pragma unroll
  for (int mi = 0; mi < 4; ++mi) {
    #pragma unroll
    for (int r = 0; r < 4; ++r) {
      int grow = row0 + wm + mi * 16 + quad * 4 + r;
      if (grow < BN) {
        #pragma unroll
        for (int ni = 0; ni < 4; ++ni) {
          int col = n0 + wn + ni * 16 + c16;
          out[(size_t)grow * 512 + col] = acc[mi][ni][r] + bout[col];
        }
      }
    }
  }
}

// ---------------- launch ----------------
extern "C" void kernel_launch(void* const* d_in, const int* in_sizes, int n_in,
                              void* d_out, int out_size, void* d_ws, size_t ws_size,
                              hipStream_t stream) {
  (void)in_sizes; (void)n_in; (void)out_size;
  if (ws_size < WS_NEEDED) return;   // fail clean, not crash
  const float* x    = (const float*)d_in[0];
  const float* Wqk  = (const float*)d_in[1];
  const float* Wv   = (const float*)d_in[2];
  const float* Wout = (const float*)d_in[3];
  const float* bout = (const float*)d_in[4];
  const float* relb = (const float*)d_in[5];
  const float* edel = (const float*)d_in[6];
  const float* ealp = (const float*)d_in[7];
  const float* ebet = (const float*)d_in[8];
  const float* egam = (const float*)d_in[9];
  const float* eome = (const float*)d_in[10];

  char* ws = (char*)d_ws;
  ushort* Wqkvt = (ushort*)(ws + OFF_WQKVT);
  ushort* Woutt = (ushort*)(ws + OFF_WOUTT);
  float*  qtab  = (float*)(ws + OFF_QTAB);
  float*  ctab  = (float*)(ws + OFF_CTAB);
  ushort* qkb   = (ushort*)(ws + OFF_QK);
  ushort* vb    = (ushort*)(ws + OFF_V);
  ushort* xm    = (ushort*)(ws + OFF_XM);
  ushort* vtb   = (ushort*)(ws + OFF_VT);
  ushort* aob   = (ushort*)(ws + OFF_AO);
  float*  stf   = (float*)(ws + OFF_ST);       // EMA chunk states (dead before fattn)
  float*  outp  = (float*)d_out;

  k_prep<<<dim3(4160), dim3(256), 0, stream>>>(edel, ealp, ebet, egam, Wqk, Wv, Wout,
                                               qtab, ctab, Wqkvt, Woutt);
  k_ema_p1<<<dim3(16, 7, 32), dim3(64), 0, stream>>>(x, qtab, stf);
  k_ema_mid<<<dim3(2048), dim3(256), 0, stream>>>(qtab, stf);
  k_ema_fuse<<<dim3(8, 8, 32), dim3(64), 0, stream>>>(x, qtab, ctab, stf, eome, xm);
  k_qkv<<<dim3(12, 145), dim3(256), 0, stream>>>(xm, Wqkvt, qkb, vb);
  k_vtrans<<<dim3(10, 256), dim3(256), 0, stream>>>(vb, vtb);
  k_fattn<<<dim3(256, 5), dim3(256), 0, stream>>>(qkb, vtb, relb, aob);
  k_out<<<dim3(4, 145), dim3(256), 0, stream>>>(aob, Woutt, bout, outp);
}

// Round 10
// 294.427 us; speedup vs baseline: 1.0182x; 1.0182x over previous
//
#include <hip/hip_runtime.h>

typedef unsigned short ushort;

typedef __bf16 bf16x8 __attribute__((ext_vector_type(8)));
typedef float  f32x4  __attribute__((ext_vector_type(4)));
typedef float  f32x2  __attribute__((ext_vector_type(2)));
typedef unsigned short u16x8 __attribute__((ext_vector_type(8)));
typedef unsigned short u16x4 __attribute__((ext_vector_type(4)));
typedef unsigned int   u32x2 __attribute__((ext_vector_type(2)));

static constexpr int BB   = 32;
static constexpr int NN   = 577;   // N = NP+1
static constexpr int LL   = 576;   // NP
static constexpr int DIMC = 512;
static constexpr int BN   = BB * NN;  // 18464

// ---------------- workspace arena (bytes), total 98,828,288 (~94.3 MB) -----
// EMA chunk-states (16.8 MB) live in the AO region (dead until k_fattn).
static constexpr size_t SZ_WQKVT = 1536ull * 512 * 2;
static constexpr size_t SZ_WOUTT = 512ull * 512 * 2;
static constexpr size_t SZ_QK    = (size_t)BN * 1024 * 2;    // 37,814,272
static constexpr size_t SZ_V     = (size_t)BN * 512 * 2;     // 18,907,136
static constexpr size_t SZ_VT    = 256ull * 64 * 640 * 2;    // 20,971,520
static constexpr size_t OFF_WQKVT = 0;
static constexpr size_t OFF_WOUTT = OFF_WQKVT + SZ_WQKVT;
static constexpr size_t OFF_QTAB  = OFF_WOUTT + SZ_WOUTT;
static constexpr size_t OFF_CTAB  = OFF_QTAB + 65536;
static constexpr size_t OFF_QK    = OFF_CTAB + 65536;
static constexpr size_t OFF_V     = OFF_QK + SZ_QK;
static constexpr size_t OFF_REGION= OFF_V + SZ_V;
static constexpr size_t OFF_XM    = OFF_REGION;              // xm dead after k_qkv
static constexpr size_t OFF_VT    = OFF_REGION;              // vt overlays xm
static constexpr size_t OFF_AO    = OFF_REGION + SZ_VT;
static constexpr size_t OFF_ST    = OFF_AO;                  // EMA states overlay ao
static constexpr size_t WS_NEEDED = OFF_AO + SZ_V;           // 98,828,288

// ---------------- helpers ----------------
__device__ __forceinline__ ushort bf16bits(float f) {
  unsigned int u = __builtin_bit_cast(unsigned int, f);
  u = (u + 0x7fffu + ((u >> 16) & 1u)) >> 16;
  return (ushort)u;
}
// RNE bf16 pair-pack: same bits as (bf16bits(lo) | bf16bits(hi)<<16).
__device__ __forceinline__ unsigned int bf16pk(float lo, float hi) {
  unsigned int u0 = __builtin_bit_cast(unsigned int, lo);
  unsigned int u1 = __builtin_bit_cast(unsigned int, hi);
  unsigned int a0 = u0 + 0x7fffu + ((u0 >> 16) & 1u);
  unsigned int a1 = u1 + 0x7fffu + ((u1 >> 16) & 1u);
  return __builtin_amdgcn_perm(a1, a0, 0x07060302);   // {a1.hi16, a0.hi16}
}
__device__ __forceinline__ float sigmoidf_(float z) { return 1.f / (1.f + __expf(-z)); }
__device__ __forceinline__ float siluf(float z)     { return z / (1.f + __expf(-z)); }
// async global->LDS, 16B per lane; linear LDS dest (base+lane*16), per-lane
// global src (pre-swizzled).
__device__ __forceinline__ void gload16(const ushort* g, ushort* l) {
  __builtin_amdgcn_global_load_lds(
      (const __attribute__((address_space(1))) unsigned int*)g,
      (__attribute__((address_space(3))) unsigned int*)l, 16, 0, 0);
}

// ---------------- prep: EMA tables + bf16 transposed weights ----------------
__global__ __launch_bounds__(256) void k_prep(
    const float* __restrict__ delta, const float* __restrict__ alpha,
    const float* __restrict__ beta,  const float* __restrict__ gamma,
    const float* __restrict__ Wqk,   const float* __restrict__ Wv,
    const float* __restrict__ Wout,
    float* __restrict__ qtab, float* __restrict__ ctab,
    ushort* __restrict__ Wqkvt, ushort* __restrict__ Woutt)
{
  int idx = blockIdx.x * 256 + threadIdx.x;
  if (idx < 16384) {
    float p = sigmoidf_(delta[idx]);
    float q = 1.f - p * sigmoidf_(alpha[idx]);
    qtab[idx] = q;
    ctab[idx] = p * beta[idx] * gamma[idx] * 0.25f;   // scale = sqrt(1/16)
  }
  int i2 = idx - 16384;                                // Wqkv_t: [1536][512]
  if (i2 >= 0 && i2 < 1536 * 512) {
    int n = i2 >> 9, k = i2 & 511;
    float w = (n < 1024) ? Wqk[k * 1024 + n] : Wv[k * 512 + (n - 1024)];
    Wqkvt[i2] = bf16bits(w);
  }
  int i3 = i2 - 1536 * 512;                            // Wout_t: [512][512]
  if (i3 >= 0 && i3 < 512 * 512) {
    int n = i3 >> 9, k = i3 & 511;
    Woutt[i3] = bf16bits(Wout[k * 512 + n]);
  }
}

// ======== chunked EMA scan (linear recurrence, q in (0,1)) =================
// f32x2[8] + elementwise_fma so LLVM can select dual-issue v_pk_fma_f32.
// st: [(dir*32+b)*8+chunk][n16][d512] f32.

// ---- pass 1: chunk-local final states, chunks 0..6 each direction --------
__global__ __launch_bounds__(64) void k_ema_p1(
    const float* __restrict__ x, const float* __restrict__ qtab,
    float* __restrict__ st)
{
  const int gx = blockIdx.x, cy = blockIdx.y, b = blockIdx.z;
  if (gx < 8) {
    const int d = gx * 64 + threadIdx.x;
    f32x2 q[8], h[8];
    #pragma unroll
    for (int n = 0; n < 8; ++n) {
      q[n] = *(const f32x2*)(qtab + d * 16 + 2 * n);
      h[n] = (f32x2){0.f, 0.f};
    }
    const float* xp = x + ((size_t)b * NN + 1) * DIMC + d;
    const int blo = cy * 9;
    float xn[8];
    #pragma unroll
    for (int u = 0; u < 8; ++u) xn[u] = xp[(blo * 8 + u) * DIMC];
    for (int blk = blo; blk < blo + 9; ++blk) {
      float xv[8];
      #pragma unroll
      for (int u = 0; u < 8; ++u) xv[u] = xn[u];
      if (blk < blo + 8) {
        #pragma unroll
        for (int u = 0; u < 8; ++u) xn[u] = xp[((blk + 1) * 8 + u) * DIMC];
      }
      #pragma unroll
      for (int u = 0; u < 8; ++u) {
        f32x2 x2 = {xv[u], xv[u]};
        #pragma unroll
        for (int n = 0; n < 8; ++n) h[n] = __builtin_elementwise_fma(q[n], h[n], x2);
      }
    }
    float* sp = st + (((size_t)b * 8 + cy) * 16) * 512 + d;
    #pragma unroll
    for (int n = 0; n < 8; ++n) { sp[(2*n) * 512] = h[n][0]; sp[(2*n+1) * 512] = h[n][1]; }
  } else {
    const int d = (gx - 8) * 64 + threadIdx.x;
    f32x2 q[8], g[8];
    #pragma unroll
    for (int n = 0; n < 8; ++n) {
      q[n] = *(const f32x2*)(qtab + (d + 512) * 16 + 2 * n);
      g[n] = (f32x2){0.f, 0.f};
    }
    const float* xp = x + ((size_t)b * NN + 1) * DIMC + d;
    const int blo = (7 - cy) * 9;
    float xn[8];
    #pragma unroll
    for (int u = 0; u < 8; ++u) xn[u] = xp[((blo + 8) * 8 + u) * DIMC];
    for (int blk = blo + 8; blk >= blo; --blk) {
      float xv[8];
      #pragma unroll
      for (int u = 0; u < 8; ++u) xv[u] = xn[u];
      if (blk > blo) {
        #pragma unroll
        for (int u = 0; u < 8; ++u) xn[u] = xp[((blk - 1) * 8 + u) * DIMC];
      }
      #pragma unroll
      for (int u = 7; u >= 0; --u) {
        f32x2 x2 = {xv[u], xv[u]};
        #pragma unroll
        for (int n = 0; n < 8; ++n) g[n] = __builtin_elementwise_fma(q[n], g[n], x2);
      }
    }
    float* sp = st + (((size_t)(32 + b) * 8 + cy) * 16) * 512 + d;
    #pragma unroll
    for (int n = 0; n < 8; ++n) { sp[(2*n) * 512] = g[n][0]; sp[(2*n+1) * 512] = g[n][1]; }
  }
}

// ---- mid: exclusive scan over chunk states with q^72 ----------------------
__global__ __launch_bounds__(256) void k_ema_mid(
    const float* __restrict__ qtab, float* __restrict__ st)
{
  int idx = blockIdx.x * 256 + threadIdx.x;   // 524,288 = 64*16*512
  int d = idx & 511;
  int rest = idx >> 9;          // db*16 + n
  int n = rest & 15;
  int db = rest >> 4;           // dir*32 + b
  int dir = db >> 5;
  float q = qtab[(((size_t)dir << 9) + d) * 16 + n];
  float q2 = q * q, q4 = q2 * q2, q8 = q4 * q4;
  float q16 = q8 * q8, q32 = q16 * q16, q64 = q32 * q32;
  float qL = q64 * q8;          // q^72
  float h = 0.f;
  float* sp = st + ((size_t)db * 128 + n) * 512 + d;
  #pragma unroll
  for (int c = 0; c < 8; ++c) {
    float tmp = (c < 7) ? sp[c * 8192] : 0.f;   // chunk stride 16*512
    sp[c * 8192] = h;
    h = fmaf(qL, h, tmp);
  }
}

// ---- fused pass 3: bwd (y2->LDS fp16) then fwd + combine + silu -> xm -----
__global__ __launch_bounds__(64) void k_ema_fuse(
    const float* __restrict__ x, const float* __restrict__ qtab,
    const float* __restrict__ ctab, const float* __restrict__ st,
    const float* __restrict__ omega, ushort* __restrict__ xm)
{
  __shared__ _Float16 yb[72 * 64];   // 9,216 B
  const int lane = threadIdx.x;
  const int gx = blockIdx.x, cy = blockIdx.y, b = blockIdx.z;
  const int d = gx * 64 + lane;
  const float* xp = x + ((size_t)b * NN + 1 + cy * 72) * DIMC + d;
  { // backward pass over this chunk's 72 rows
    f32x2 q[8], c[8], g[8];
    const float* sp = st + (((size_t)(32 + b) * 8 + (7 - cy)) * 16) * 512 + d;
    #pragma unroll
    for (int n = 0; n < 8; ++n) {
      q[n] = *(const f32x2*)(qtab + (d + 512) * 16 + 2 * n);
      c[n] = *(const f32x2*)(ctab + (d + 512) * 16 + 2 * n);
      g[n] = (f32x2){sp[(2*n) * 512], sp[(2*n+1) * 512]};
    }
    float xn[8];
    #pragma unroll
    for (int u = 0; u < 8; ++u) xn[u] = xp[(64 + u) * DIMC];
    for (int blk = 8; blk >= 0; --blk) {
      float xv[8];
      #pragma unroll
      for (int u = 0; u < 8; ++u) xv[u] = xn[u];
      if (blk > 0) {
        #pragma unroll
        for (int u = 0; u < 8; ++u) xn[u] = xp[((blk - 1) * 8 + u) * DIMC];
      }
      #pragma unroll
      for (int u = 7; u >= 0; --u) {
        f32x2 x2 = {xv[u], xv[u]};
        f32x2 yv = {0.f, 0.f};
        #pragma unroll
        for (int n = 0; n < 8; ++n) {
          g[n] = __builtin_elementwise_fma(q[n], g[n], x2);
          yv   = __builtin_elementwise_fma(c[n], g[n], yv);
        }
        yb[(blk * 8 + u) * 64 + lane] = (_Float16)(yv[0] + yv[1]);
      }
    }
  }
  __syncthreads();
  { // forward pass + combine
    f32x2 q[8], c[8], h[8];
    const float* sp = st + (((size_t)b * 8 + cy) * 16) * 512 + d;
    #pragma unroll
    for (int n = 0; n < 8; ++n) {
      q[n] = *(const f32x2*)(qtab + d * 16 + 2 * n);
      c[n] = *(const f32x2*)(ctab + d * 16 + 2 * n);
      h[n] = (f32x2){sp[(2*n) * 512], sp[(2*n+1) * 512]};
    }
    const float om = omega[d];
    ushort* op = xm + ((size_t)b * NN + 1 + cy * 72) * DIMC + d;
    float xn[8];
    #pragma unroll
    for (int u = 0; u < 8; ++u) xn[u] = xp[u * DIMC];
    for (int blk = 0; blk < 9; ++blk) {
      float xv[8];
      #pragma unroll
      for (int u = 0; u < 8; ++u) xv[u] = xn[u];
      if (blk < 8) {
        #pragma unroll
        for (int u = 0; u < 8; ++u) xn[u] = xp[((blk + 1) * 8 + u) * DIMC];
      }
      #pragma unroll
      for (int u = 0; u < 8; ++u) {
        f32x2 x2 = {xv[u], xv[u]};
        f32x2 yv = {0.f, 0.f};
        #pragma unroll
        for (int n = 0; n < 8; ++n) {
          h[n] = __builtin_elementwise_fma(q[n], h[n], x2);
          yv   = __builtin_elementwise_fma(c[n], h[n], yv);
        }
        float s = (yv[0] + yv[1]) + (float)yb[(blk * 8 + u) * 64 + lane] + xv[u] * om;
        op[(blk * 8 + u) * DIMC] = bf16bits(siluf(s));
      }
    }
  }
  if (cy == 0) {   // cls row passthrough
    size_t e0 = ((size_t)b * NN) * DIMC + d;
    xm[e0] = bf16bits(x[e0]);
  }
}

// ---------------- QKV GEMM: xm[18464,512] @ Wqkv_t[1536,512]^T -------------
// global_load_lds staging; LINEAR LDS [128][32]; source col pre-swizzled by
// (row&3), same XOR on MFMA read. q cols pre-scaled by 0.125*log2(e).
// XCD-chunked block remap (bijective, nwg=1740).
// EPILOGUE: LDS-staged coalesced stores (u16x8/lane).
__global__ __launch_bounds__(256) void k_qkv(
    const ushort* __restrict__ A, const ushort* __restrict__ Bt,
    ushort* __restrict__ qk, ushort* __restrict__ v)
{
  __shared__ alignas(16) ushort lsh[8192];     // 16 KB: lA | lB, reused by epilogue
  ushort* lA = lsh;
  ushort* lB = lsh + 4096;
  const int tid = threadIdx.x, wv = tid >> 6, lane = tid & 63;
  const int quad = lane >> 4, c16 = lane & 15;
  const int fid = blockIdx.y * 12 + blockIdx.x;        // dispatch-order id
  const int xcd = fid & 7, ord = fid >> 3;             // nwg=1740: q=217,r=4
  const int wg  = (xcd < 4 ? xcd * 218 : 872 + (xcd - 4) * 217) + ord;
  const int row0 = (wg / 12) * 128, n0 = (wg % 12) * 128;
  const int wm = (wv >> 1) * 64, wn = (wv & 1) * 64;
  const int sr  = wv * 32 + (lane >> 2);
  const int scs = ((lane & 3) ^ (sr & 3)) * 8;         // source col swizzle
  int ga[2], gb[2];
  #pragma unroll
  for (int s = 0; s < 2; ++s) {
    int r = row0 + sr + s * 16; if (r > BN - 1) r = BN - 1;
    ga[s] = r;
    gb[s] = n0 + sr + s * 16;
  }
  const int xread = (quad ^ (c16 & 3)) * 8;            // MFMA read swizzle
  f32x4 z4 = {0.f, 0.f, 0.f, 0.f};
  f32x4 acc[4][4];
  #pragma unroll
  for (int mi = 0; mi < 4; ++mi)
    #pragma unroll
    for (int ni = 0; ni < 4; ++ni) acc[mi][ni] = z4;

  for (int kt = 0; kt < 16; ++kt) {
    const int k0 = kt * 32;
    __syncthreads();                 // prior MFMA reads done
    #pragma unroll
    for (int s = 0; s < 2; ++s) {
      gload16(A  + (size_t)ga[s] * 512 + k0 + scs, lA + (wv * 32 + s * 16) * 32);
      gload16(Bt + (size_t)gb[s] * 512 + k0 + scs, lB + (wv * 32 + s * 16) * 32);
    }
    __syncthreads();                 // vmcnt drained -> tile visible
    bf16x8 af[4], bfv[4];
    #pragma unroll
    for (int mi = 0; mi < 4; ++mi)
      af[mi] = *(const bf16x8*)(lA + (wm + mi * 16 + c16) * 32 + xread);
    #pragma unroll
    for (int ni = 0; ni < 4; ++ni)
      bfv[ni] = *(const bf16x8*)(lB + (wn + ni * 16 + c16) * 32 + xread);
    #pragma unroll
    for (int mi = 0; mi < 4; ++mi)
      #pragma unroll
      for (int ni = 0; ni < 4; ++ni)
        acc[mi][ni] = __builtin_amdgcn_mfma_f32_16x16x32_bf16(af[mi], bfv[ni], acc[mi][ni], 0, 0, 0);
  }
  const bool isv = (n0 >= 1024);
  const float osc = (n0 < 512) ? 0.1803368801111f : 1.0f;  // 0.125*log2(e)
  // ---- epilogue: stage half-tile [64][128] bf16 in lsh, store coalesced
  #pragma unroll
  for (int hh = 0; hh < 2; ++hh) {
    __syncthreads();                 // prior half's readers / MFMA reads done
    if ((wv >> 1) == hh) {
      #pragma unroll
      for (int mi = 0; mi < 4; ++mi)
        #pragma unroll
        for (int r = 0; r < 4; ++r) {
          int lrow = mi * 16 + quad * 4 + r;           // 0..63 within half
          #pragma unroll
          for (int ni = 0; ni < 4; ++ni)
            lsh[lrow * 128 + wn + ni * 16 + c16] = bf16bits(acc[mi][ni][r] * osc);
        }
    }
    __syncthreads();                 // half-tile visible
    #pragma unroll
    for (int pass = 0; pass < 4; ++pass) {
      int lrow = pass * 16 + (tid >> 4);
      int cc = (tid & 15) * 8;
      int grow = row0 + hh * 64 + lrow;
      if (grow < BN) {
        u16x8 val = *(const u16x8*)(lsh + lrow * 128 + cc);
        if (!isv) *(u16x8*)(qk + (size_t)grow * 1024 + n0 + cc) = val;
        else      *(u16x8*)(v  + (size_t)grow * 512 + (n0 - 1024) + cc) = val;
      }
    }
  }
}

// ---------------- transpose v -> vt[bh*64+dh][640] (zero-padded j>=577) ----
__global__ __launch_bounds__(256) void k_vtrans(
    const ushort* __restrict__ v, ushort* __restrict__ vt)
{
  __shared__ alignas(16) ushort lt[64 * 72];
  const int tid = threadIdx.x;
  const int bh = blockIdx.y, b = bh >> 3, h = bh & 7;
  const int j0 = blockIdx.x * 64;
  #pragma unroll
  for (int pass = 0; pass < 2; ++pass) {
    int cch = pass * 256 + tid;
    int jl = cch >> 3, cc = cch & 7;
    int gj = j0 + jl;
    u16x8 val = {0, 0, 0, 0, 0, 0, 0, 0};
    if (gj < 577) val = *(const u16x8*)(v + ((size_t)(b * NN + gj)) * 512 + h * 64 + cc * 8);
    *(u16x8*)(lt + jl * 72 + cc * 8) = val;
  }
  __syncthreads();
  #pragma unroll
  for (int pass = 0; pass < 2; ++pass) {
    int cch = pass * 256 + tid;
    int dh = cch >> 3, jc = cch & 7;
    u16x8 o;
    #pragma unroll
    for (int e = 0; e < 8; ++e) o[e] = lt[(jc * 8 + e) * 72 + dh];
    *(u16x8*)(vt + ((size_t)(bh * 64 + dh)) * 640 + j0 + jc * 8) = o;
  }
}

// -------- fused flash attention: O = softmax(QK^T) V + Bias V --------------
// 512-THREAD / 8-WAVE blocks, 128-row tile: combines r6's block geometry
// (staging amortized over 128 rows, FETCH ~72 MB, grid (256,5)) with r7's
// 16-rows-per-wave body (arch VGPR ~72 + 32 acc ~= 104 <= 128/wave -> 4
// waves/SIMD, 2 blocks/CU = 16 waves/CU vs r6's ~8). r6 limiter was regs:
// 124+64acc -> 2 waves/SIMD, 19% occupancy.
// Static softmax; Q pre-scaled 0.125*log2(e) -> raw exp2; swapped QK^T;
// RNE pair-pack; lp wave-private (2 barriers/tile); reg-prefetch staging
// (r8 showed gload_lds-dbuf regresses here).
__global__ __launch_bounds__(512) void k_fattn(
    const ushort* __restrict__ qk, const ushort* __restrict__ vt,
    const float* __restrict__ relb, ushort* __restrict__ ao)
{
  __shared__ alignas(16) ushort lk[64 * 64];
  __shared__ alignas(16) ushort lv[64 * 64];
  __shared__ alignas(16) ushort lp[128 * 64];
  __shared__ ushort lbias16[1280];     // bf16 bias at +64 offset, pad-safe
  const int tid = threadIdx.x, wv = tid >> 6, lane = tid & 63;
  const int quad = lane >> 4, c16 = lane & 15;
  const int bh = blockIdx.x, b = bh >> 3, h = bh & 7;
  const int i0 = blockIdx.y * 128, wm = wv * 16;
  for (int t = tid; t < 1280; t += 512) {
    int idx = t - 64;
    lbias16[t] = (idx >= 0 && idx < 1153) ? bf16bits(relb[idx]) : (ushort)0;
  }
  // Q fragments in registers (wave's 16 rows: i0+wm+c16)
  bf16x8 aq[2];
  {
    int gi = i0 + wm + c16; if (gi > 576) gi = 576;
    const ushort* qp = qk + ((size_t)(b * NN + gi)) * 1024 + h * 64;
    #pragma unroll
    for (int kk = 0; kk < 2; ++kk)
      aq[kk] = *(const bf16x8*)(qp + (kk * 4 + quad) * 8);
  }
  // staging: 512 threads, 1 K-chunk + 1 V-chunk (u16x8) each.
  const int s_r = tid >> 3, s_c = tid & 7;
  const ushort* kbase = qk + ((size_t)b * NN) * 1024 + 512 + h * 64 + s_c * 8;
  const ushort* vbase = vt + ((size_t)bh * 64) * 640 + s_c * 8;

  float lsum = 0.f;
  f32x4 z4 = {0.f, 0.f, 0.f, 0.f};
  f32x4 accp[4], accb[4];
  #pragma unroll
  for (int ns = 0; ns < 4; ++ns) { accp[ns] = z4; accb[ns] = z4; }

  // preload tile jt=0 (j = 0..63, no clamp needed)
  u16x8 sk, sv;
  sk = *(const u16x8*)(kbase + (size_t)s_r * 1024);
  sv = *(const u16x8*)(vbase + (size_t)s_r * 640);

  for (int jt = 0; jt < 10; ++jt) {
    __syncthreads();                       // prior lk/lv readers done
    {
      int pc = (s_c ^ (s_r & 7)) * 8;
      *(u16x8*)(lk + s_r * 64 + pc) = sk;
      *(u16x8*)(lv + s_r * 64 + pc) = sv;
    }
    __syncthreads();                       // staging visible
    // issue next K/V tile loads NOW: latency hides under QK^T+softmax+PV
    if (jt < 9) {
      const int j0n = (jt + 1) * 64;
      int gj = j0n + s_r; if (gj > 576) gj = 576;
      sk = *(const u16x8*)(kbase + (size_t)gj * 1024);
      sv = *(const u16x8*)(vbase + (size_t)s_r * 640 + j0n);
    }
    // ---- S^T = K Q^T; softmax fused
    f32x4 dacc[4] = {z4, z4, z4, z4};
    #pragma unroll
    for (int kk = 0; kk < 2; ++kk) {
      const int ck = kk * 4 + quad;
      #pragma unroll
      for (int ns = 0; ns < 4; ++ns) {
        const int row = ns * 16 + c16;
        bf16x8 bk = *(const bf16x8*)(lk + row * 64 + ((ck ^ (row & 7)) * 8));
        dacc[ns] = __builtin_amdgcn_mfma_f32_16x16x32_bf16(bk, aq[kk], dacc[ns], 0, 0, 0);
      }
    }
    // lane holds S[i = wm+c16][j = jt*64 + ns*16 + quad*4 + r]
    {
      const int irow = wm + c16;
      const int xr = irow & 7;
      #pragma unroll
      for (int ns = 0; ns < 4; ++ns) {
        float ex[4];
        #pragma unroll
        for (int r = 0; r < 4; ++r) {
          float e = __builtin_amdgcn_exp2f(dacc[ns][r]);
          if (jt == 9 && (ns * 16 + quad * 4 + r) >= 1) e = 0.f;   // j >= 577
          ex[r] = e;
        }
        lsum += (ex[0] + ex[1]) + (ex[2] + ex[3]);
        u32x2 pw = { bf16pk(ex[0], ex[1]), bf16pk(ex[2], ex[3]) };
        const int lc2 = ns * 2 + (quad >> 1);        // logical 8-col chunk
        *(u32x2*)(lp + irow * 64 + ((lc2 ^ xr) * 8) + (quad & 1) * 4) = pw;
      }
    }
    // (no barrier: lp rows are wave-private; lgkmcnt orders)
    // ---- O += P~ V  and  O_b += Bias V
    const int j0 = jt * 64;
    #pragma unroll
    for (int kk = 0; kk < 2; ++kk) {
      const int ck = kk * 4 + quad;
      const int row = wm + c16;
      bf16x8 ap = *(const bf16x8*)(lp + row * 64 + ((ck ^ (row & 7)) * 8));
      u16x8 abu;
      const int base = 64 + 576 + j0 + kk * 32 + quad * 8 - (i0 + row);
      #pragma unroll
      for (int e = 0; e < 8; ++e) abu[e] = lbias16[base + e];
      bf16x8 ab = __builtin_bit_cast(bf16x8, abu);
      #pragma unroll
      for (int ns = 0; ns < 4; ++ns) {
        const int vrow = ns * 16 + c16;
        bf16x8 bV = *(const bf16x8*)(lv + vrow * 64 + ((ck ^ (vrow & 7)) * 8));
        accp[ns] = __builtin_amdgcn_mfma_f32_16x16x32_bf16(ap, bV, accp[ns], 0, 0, 0);
        accb[ns] = __builtin_amdgcn_mfma_f32_16x16x32_bf16(ab, bV, accb[ns], 0, 0, 0);
      }
    }
  }
  // ---- epilogue: lane holds row (wm+c16) sum; quad-reduce; shfl picks rows
  float tot = lsum;
  tot += __shfl_xor(tot, 16);
  tot += __shfl_xor(tot, 32);
  #pragma unroll
  for (int r = 0; r < 4; ++r) {
    float li = 1.f / __shfl(tot, quad * 4 + r);
    int ii = i0 + wm + quad * 4 + r;
    if (ii < 577) {
      #pragma unroll
      for (int ns = 0; ns < 4; ++ns)
        ao[((size_t)(b * NN + ii)) * 512 + h * 64 + ns * 16 + c16] =
            bf16bits(accp[ns][r] * li + accb[ns][r]);
    }
  }
}

// ---------------- out GEMM: ao[18464,512] @ Wout_t[512,512]^T + b_out -----
__global__ __launch_bounds__(256) void k_out(
    const ushort* __restrict__ A, const ushort* __restrict__ Bt,
    const float* __restrict__ bout, float* __restrict__ out)
{
  __shared__ alignas(16) ushort lA[128 * 32];
  __shared__ alignas(16) ushort lB[128 * 32];
  const int tid = threadIdx.x, wv = tid >> 6, lane = tid & 63;
  const int quad = lane >> 4, c16 = lane & 15;
  const int row0 = blockIdx.y * 128, n0 = blockIdx.x * 128;
  const int wm = (wv >> 1) * 64, wn = (wv & 1) * 64;
  const int sr  = wv * 32 + (lane >> 2);
  const int scs = ((lane & 3) ^ (sr & 3)) * 8;
  int ga[2], gb[2];
  #pragma unroll
  for (int s = 0; s < 2; ++s) {
    int r = row0 + sr + s * 16; if (r > BN - 1) r = BN - 1;
    ga[s] = r;
    gb[s] = n0 + sr + s * 16;
  }
  const int xread = (quad ^ (c16 & 3)) * 8;
  f32x4 z4 = {0.f, 0.f, 0.f, 0.f};
  f32x4 acc[4][4];
  #pragma unroll
  for (int mi = 0; mi < 4; ++mi)
    #pragma unroll
    for (int ni = 0; ni < 4; ++ni) acc[mi][ni] = z4;

  for (int kt = 0; kt < 16; ++kt) {
    const int k0 = kt * 32;
    __syncthreads();
    #pragma unroll
    for (int s = 0; s < 2; ++s) {
      gload16(A  + (size_t)ga[s] * 512 + k0 + scs, lA + (wv * 32 + s * 16) * 32);
      gload16(Bt + (size_t)gb[s] * 512 + k0 + scs, lB + (wv * 32 + s * 16) * 32);
    }
    __syncthreads();
    bf16x8 af[4], bfv[4];
    #pragma unroll
    for (int mi = 0; mi < 4; ++mi)
      af[mi] = *(const bf16x8*)(lA + (wm + mi * 16 + c16) * 32 + xread);
    #pragma unroll
    for (int ni = 0; ni < 4; ++ni)
      bfv[ni] = *(const bf16x8*)(lB + (wn + ni * 16 + c16) * 32 + xread);
    #pragma unroll
    for (int mi = 0; mi < 4; ++mi)
      #pragma unroll
      for (int ni = 0; ni < 4; ++ni)
        acc[mi][ni] = __builtin_amdgcn_mfma_f32_16x16x32_bf16(af[mi], bfv[ni], acc[mi][ni], 0, 0, 0);
  }
  #pragma unroll
  for (int mi = 0; mi < 4; ++mi) {
    #pragma unroll
    for (int r = 0; r < 4; ++r) {
      int grow = row0 + wm + mi * 16 + quad * 4 + r;
      if (grow < BN) {
        #pragma unroll
        for (int ni = 0; ni < 4; ++ni) {
          int col = n0 + wn + ni * 16 + c16;
          out[(size_t)grow * 512 + col] = acc[mi][ni][r] + bout[col];
        }
      }
    }
  }
}

// ---------------- launch ----------------
extern "C" void kernel_launch(void* const* d_in, const int* in_sizes, int n_in,
                              void* d_out, int out_size, void* d_ws, size_t ws_size,
                              hipStream_t stream) {
  (void)in_sizes; (void)n_in; (void)out_size;
  if (ws_size < WS_NEEDED) return;   // fail clean, not crash
  const float* x    = (const float*)d_in[0];
  const float* Wqk  = (const float*)d_in[1];
  const float* Wv   = (const float*)d_in[2];
  const float* Wout = (const float*)d_in[3];
  const float* bout = (const float*)d_in[4];
  const float* relb = (const float*)d_in[5];
  const float* edel = (const float*)d_in[6];
  const float* ealp = (const float*)d_in[7];
  const float* ebet = (const float*)d_in[8];
  const float* egam = (const float*)d_in[9];
  const float* eome = (const float*)d_in[10];

  char* ws = (char*)d_ws;
  ushort* Wqkvt = (ushort*)(ws + OFF_WQKVT);
  ushort* Woutt = (ushort*)(ws + OFF_WOUTT);
  float*  qtab  = (float*)(ws + OFF_QTAB);
  float*  ctab  = (float*)(ws + OFF_CTAB);
  ushort* qkb   = (ushort*)(ws + OFF_QK);
  ushort* vb    = (ushort*)(ws + OFF_V);
  ushort* xm    = (ushort*)(ws + OFF_XM);
  ushort* vtb   = (ushort*)(ws + OFF_VT);
  ushort* aob   = (ushort*)(ws + OFF_AO);
  float*  stf   = (float*)(ws + OFF_ST);       // EMA chunk states (dead before fattn)
  float*  outp  = (float*)d_out;

  k_prep<<<dim3(4160), dim3(256), 0, stream>>>(edel, ealp, ebet, egam, Wqk, Wv, Wout,
                                               qtab, ctab, Wqkvt, Woutt);
  k_ema_p1<<<dim3(16, 7, 32), dim3(64), 0, stream>>>(x, qtab, stf);
  k_ema_mid<<<dim3(2048), dim3(256), 0, stream>>>(qtab, stf);
  k_ema_fuse<<<dim3(8, 8, 32), dim3(64), 0, stream>>>(x, qtab, ctab, stf, eome, xm);
  k_qkv<<<dim3(12, 145), dim3(256), 0, stream>>>(xm, Wqkvt, qkb, vb);
  k_vtrans<<<dim3(10, 256), dim3(256), 0, stream>>>(vb, vtb);
  k_fattn<<<dim3(256, 5), dim3(512), 0, stream>>>(qkb, vtb, relb, aob);
  k_out<<<dim3(4, 145), dim3(256), 0, stream>>>(aob, Woutt, bout, outp);
}